// Round 4
// baseline (50.724 us; speedup 1.0000x reference)
//
#include <hip/hip_runtime.h>
#include <math.h>

// Problem constants (from reference: x = (2,2,160,160,160) fp32)
#define BCn 4
#define Dn 160
#define Hn 160
#define Wn 160
#define HWn (Hn * Wn)
#define W4q (Wn / 4)        // 40 float4 groups per row
#define COLS (Hn * W4q)     // 6400 (h, q) columns per plane
#define DCHUNK 4
#define BLOCK 256

// Raw (unreduced) loads for one z-plane's 3-row neighborhood of a 4-wide
// output group: 3 coalesced float4 loads + 6 edge scalars.
struct Raw {
  float4 vm, v0, vp;
  float m0, m5, c0, c5, q0, q5;
};

// Reduced per-plane state:
//   Rs = 3x3 window sums (feeds gd), Rd = row(h+1)-row(h-1) sums (feeds gh),
//   Cs = col(w+1)-col(w-1) sums (feeds gw).
struct Plane {
  float4 Rs, Rd, Cs;
};

__device__ __forceinline__ Raw load_raw(const float* __restrict__ xb, int zz,
                                        int rm, int r0, int rp, int w4,
                                        int km, int kp) {
  const int zc = zz < 0 ? 0 : (zz > Dn - 1 ? Dn - 1 : zz);
  const float* p = xb + (size_t)zc * HWn;
  Raw r;
  r.vm = *(const float4*)(p + rm + w4);
  r.v0 = *(const float4*)(p + r0 + w4);
  r.vp = *(const float4*)(p + rp + w4);
  r.m0 = p[rm + w4 + km]; r.m5 = p[rm + w4 + kp];
  r.c0 = p[r0 + w4 + km]; r.c5 = p[r0 + w4 + kp];
  r.q0 = p[rp + w4 + km]; r.q5 = p[rp + w4 + kp];
  return r;
}

__device__ __forceinline__ Plane reduce_raw(const Raw& r) {
  const float s0 = r.m0 + r.c0 + r.q0;
  const float s1 = r.vm.x + r.v0.x + r.vp.x;
  const float s2 = r.vm.y + r.v0.y + r.vp.y;
  const float s3 = r.vm.z + r.v0.z + r.vp.z;
  const float s4 = r.vm.w + r.v0.w + r.vp.w;
  const float s5 = r.m5 + r.c5 + r.q5;
  const float d0 = r.q0 - r.m0;
  const float d1 = r.vp.x - r.vm.x;
  const float d2 = r.vp.y - r.vm.y;
  const float d3 = r.vp.z - r.vm.z;
  const float d4 = r.vp.w - r.vm.w;
  const float d5 = r.q5 - r.m5;

  Plane out;
  const float t12 = s1 + s2, t23 = s2 + s3, t34 = s3 + s4;
  out.Rs.x = s0 + t12;
  out.Rs.y = t12 + s3;
  out.Rs.z = t23 + s4;
  out.Rs.w = t34 + s5;
  out.Rd.x = d0 + d1 + d2;
  out.Rd.y = d1 + d2 + d3;
  out.Rd.z = d2 + d3 + d4;
  out.Rd.w = d3 + d4 + d5;
  out.Cs.x = s2 - s0;
  out.Cs.y = s3 - s1;
  out.Cs.z = s4 - s2;
  out.Cs.w = s5 - s3;
  return out;
}

__device__ __forceinline__ float4 mag4(const Plane& P0, const Plane& P1,
                                       const Plane& P2) {
  const float gdx = P2.Rs.x - P0.Rs.x;
  const float gdy = P2.Rs.y - P0.Rs.y;
  const float gdz = P2.Rs.z - P0.Rs.z;
  const float gdw = P2.Rs.w - P0.Rs.w;
  const float ghx = P0.Rd.x + P1.Rd.x + P2.Rd.x;
  const float ghy = P0.Rd.y + P1.Rd.y + P2.Rd.y;
  const float ghz = P0.Rd.z + P1.Rd.z + P2.Rd.z;
  const float ghw = P0.Rd.w + P1.Rd.w + P2.Rd.w;
  const float gwx = P0.Cs.x + P1.Cs.x + P2.Cs.x;
  const float gwy = P0.Cs.y + P1.Cs.y + P2.Cs.y;
  const float gwz = P0.Cs.z + P1.Cs.z + P2.Cs.z;
  const float gww = P0.Cs.w + P1.Cs.w + P2.Cs.w;
  float4 g;
  g.x = sqrtf(gdx * gdx + ghx * ghx + gwx * gwx);
  g.y = sqrtf(gdy * gdy + ghy * ghy + gwy * gwy);
  g.z = sqrtf(gdz * gdz + ghz * ghz + gwz * gwz);
  g.w = sqrtf(gdw * gdw + ghw * ghw + gww * gww);
  return g;
}

__global__ __launch_bounds__(BLOCK) void sobel3d_mag_kernel(
    const float* __restrict__ x, float* __restrict__ out) {
  const int col4 = blockIdx.x * BLOCK + threadIdx.x;  // (h, q), 0..6399
  const int h = col4 / W4q;
  const int q = col4 - h * W4q;
  const int w4 = q * 4;
  const int bc = blockIdx.z;
  const int d0 = blockIdx.y * DCHUNK;

  const float* xb = x + (size_t)bc * Dn * HWn;
  float* ob = out + (size_t)bc * Dn * HWn;

  const int hm = (h > 0) ? h - 1 : 0;
  const int hp = (h < Hn - 1) ? h + 1 : Hn - 1;
  const int rm = hm * Wn;
  const int r0 = h * Wn;
  const int rp = hp * Wn;
  const int km = (q == 0) ? 0 : -1;
  const int kp = (q == W4q - 1) ? 3 : 4;

  // Prime: planes d0-1, d0 reduced; plane d0+1 in flight.
  Raw rA = load_raw(xb, d0 - 1, rm, r0, rp, w4, km, kp);
  Raw rB = load_raw(xb, d0, rm, r0, rp, w4, km, kp);
  Raw rC = load_raw(xb, d0 + 1, rm, r0, rp, w4, km, kp);
  Plane P0 = reduce_raw(rA);
  Plane P1 = reduce_raw(rB);

#pragma unroll
  for (int i = 0; i < DCHUNK - 1; ++i) {
    const int z = d0 + i;
    Raw rN = load_raw(xb, z + 2, rm, r0, rp, w4, km, kp);
    Plane P2 = reduce_raw(rC);
    *(float4*)(ob + (size_t)z * HWn + r0 + w4) = mag4(P0, P1, P2);
    P0 = P1;
    P1 = P2;
    rC = rN;
  }
  {
    const int z = d0 + DCHUNK - 1;
    Plane P2 = reduce_raw(rC);
    *(float4*)(ob + (size_t)z * HWn + r0 + w4) = mag4(P0, P1, P2);
  }
}

extern "C" void kernel_launch(void* const* d_in, const int* in_sizes, int n_in,
                              void* d_out, int out_size, void* d_ws, size_t ws_size,
                              hipStream_t stream) {
  const float* x = (const float*)d_in[0];
  float* out = (float*)d_out;

  dim3 block(BLOCK);
  dim3 grid(COLS / BLOCK, Dn / DCHUNK, BCn);  // (25, 40, 4) = 4000 blocks
  sobel3d_mag_kernel<<<grid, block, 0, stream>>>(x, out);
}

// Round 5
// 50.068 us; speedup vs baseline: 1.0131x; 1.0131x over previous
//
#include <hip/hip_runtime.h>
#include <math.h>

// Problem constants (from reference: x = (2,2,160,160,160) fp32)
#define BCn 4
#define Dn 160
#define Hn 160
#define Wn 160
#define HWn (Hn * Wn)
#define W4q (Wn / 4)        // 40 float4 groups per row
#define COLS (Hn * W4q)     // 6400 (h, q) columns per plane
#define DCHUNK 4
#define BLOCK 256

// Raw (unreduced) loads for one z-plane's 3-row neighborhood of a 4-wide
// output group: 3 coalesced float4 loads + 6 edge scalars.
struct Raw {
  float4 vm, v0, vp;
  float m0, m5, c0, c5, q0, q5;
};

// Reduced per-plane state:
//   Rs = 3x3 window sums (feeds gd), Rd = row(h+1)-row(h-1) sums (feeds gh),
//   Cs = col(w+1)-col(w-1) sums (feeds gw).
struct Plane {
  float4 Rs, Rd, Cs;
};

__device__ __forceinline__ Raw load_raw(const float* __restrict__ xb, int zz,
                                        int rm, int r0, int rp, int w4,
                                        int km, int kp) {
  const int zc = zz < 0 ? 0 : (zz > Dn - 1 ? Dn - 1 : zz);
  const float* p = xb + (size_t)zc * HWn;
  Raw r;
  r.vm = *(const float4*)(p + rm + w4);
  r.v0 = *(const float4*)(p + r0 + w4);
  r.vp = *(const float4*)(p + rp + w4);
  r.m0 = p[rm + w4 + km]; r.m5 = p[rm + w4 + kp];
  r.c0 = p[r0 + w4 + km]; r.c5 = p[r0 + w4 + kp];
  r.q0 = p[rp + w4 + km]; r.q5 = p[rp + w4 + kp];
  return r;
}

// Keep every field of a Raw live (defeat load-sinking/DCE across the
// sched_barrier; guide rule #17/#18).
__device__ __forceinline__ void keep_alive(Raw& r) {
  asm volatile("" : "+v"(r.vm.x), "+v"(r.vm.y), "+v"(r.vm.z), "+v"(r.vm.w),
                    "+v"(r.v0.x), "+v"(r.v0.y), "+v"(r.v0.z), "+v"(r.v0.w));
  asm volatile("" : "+v"(r.vp.x), "+v"(r.vp.y), "+v"(r.vp.z), "+v"(r.vp.w),
                    "+v"(r.m0), "+v"(r.m5), "+v"(r.c0), "+v"(r.c5));
  asm volatile("" : "+v"(r.q0), "+v"(r.q5));
}

__device__ __forceinline__ Plane reduce_raw(const Raw& r) {
  const float s0 = r.m0 + r.c0 + r.q0;
  const float s1 = r.vm.x + r.v0.x + r.vp.x;
  const float s2 = r.vm.y + r.v0.y + r.vp.y;
  const float s3 = r.vm.z + r.v0.z + r.vp.z;
  const float s4 = r.vm.w + r.v0.w + r.vp.w;
  const float s5 = r.m5 + r.c5 + r.q5;
  const float d0 = r.q0 - r.m0;
  const float d1 = r.vp.x - r.vm.x;
  const float d2 = r.vp.y - r.vm.y;
  const float d3 = r.vp.z - r.vm.z;
  const float d4 = r.vp.w - r.vm.w;
  const float d5 = r.q5 - r.m5;

  Plane out;
  const float t12 = s1 + s2, t23 = s2 + s3, t34 = s3 + s4;
  out.Rs.x = s0 + t12;
  out.Rs.y = t12 + s3;
  out.Rs.z = t23 + s4;
  out.Rs.w = t34 + s5;
  out.Rd.x = d0 + d1 + d2;
  out.Rd.y = d1 + d2 + d3;
  out.Rd.z = d2 + d3 + d4;
  out.Rd.w = d3 + d4 + d5;
  out.Cs.x = s2 - s0;
  out.Cs.y = s3 - s1;
  out.Cs.z = s4 - s2;
  out.Cs.w = s5 - s3;
  return out;
}

__device__ __forceinline__ float4 mag4(const Plane& P0, const Plane& P1,
                                       const Plane& P2) {
  const float gdx = P2.Rs.x - P0.Rs.x;
  const float gdy = P2.Rs.y - P0.Rs.y;
  const float gdz = P2.Rs.z - P0.Rs.z;
  const float gdw = P2.Rs.w - P0.Rs.w;
  const float ghx = P0.Rd.x + P1.Rd.x + P2.Rd.x;
  const float ghy = P0.Rd.y + P1.Rd.y + P2.Rd.y;
  const float ghz = P0.Rd.z + P1.Rd.z + P2.Rd.z;
  const float ghw = P0.Rd.w + P1.Rd.w + P2.Rd.w;
  const float gwx = P0.Cs.x + P1.Cs.x + P2.Cs.x;
  const float gwy = P0.Cs.y + P1.Cs.y + P2.Cs.y;
  const float gwz = P0.Cs.z + P1.Cs.z + P2.Cs.z;
  const float gww = P0.Cs.w + P1.Cs.w + P2.Cs.w;
  float4 g;
  g.x = sqrtf(gdx * gdx + ghx * ghx + gwx * gwx);
  g.y = sqrtf(gdy * gdy + ghy * ghy + gwy * gwy);
  g.z = sqrtf(gdz * gdz + ghz * ghz + gwz * gwz);
  g.w = sqrtf(gdw * gdw + ghw * ghw + gww * gww);
  return g;
}

__global__ __launch_bounds__(BLOCK) void sobel3d_mag_kernel(
    const float* __restrict__ x, float* __restrict__ out) {
  const int col4 = blockIdx.x * BLOCK + threadIdx.x;  // (h, q), 0..6399
  const int h = col4 / W4q;
  const int q = col4 - h * W4q;
  const int w4 = q * 4;
  const int bc = blockIdx.z;
  const int d0 = blockIdx.y * DCHUNK;

  const float* xb = x + (size_t)bc * Dn * HWn;
  float* ob = out + (size_t)bc * Dn * HWn;

  const int hm = (h > 0) ? h - 1 : 0;
  const int hp = (h < Hn - 1) ? h + 1 : Hn - 1;
  const int rm = hm * Wn;
  const int r0 = h * Wn;
  const int rp = hp * Wn;
  const int km = (q == 0) ? 0 : -1;
  const int kp = (q == W4q - 1) ? 3 : 4;

  // Prime: planes d0-1, d0 reduced; plane d0+1 loads in flight (pinned).
  Raw rA = load_raw(xb, d0 - 1, rm, r0, rp, w4, km, kp);
  Raw rB = load_raw(xb, d0, rm, r0, rp, w4, km, kp);
  Raw rC = load_raw(xb, d0 + 1, rm, r0, rp, w4, km, kp);
  keep_alive(rC);
  __builtin_amdgcn_sched_barrier(0);
  Plane P0 = reduce_raw(rA);
  Plane P1 = reduce_raw(rB);

#pragma unroll
  for (int i = 0; i < DCHUNK - 1; ++i) {
    const int z = d0 + i;
    // Issue next plane's loads FIRST, then fence the scheduler so they are
    // not sunk down to their use (R3/R4 post-mortem: VGPR=40 proved the
    // compiler defeated the source-level prefetch).
    Raw rN = load_raw(xb, z + 2, rm, r0, rp, w4, km, kp);
    keep_alive(rN);
    __builtin_amdgcn_sched_barrier(0);
    // Consume plane z+1, whose loads were issued one full iteration ago.
    Plane P2 = reduce_raw(rC);
    *(float4*)(ob + (size_t)z * HWn + r0 + w4) = mag4(P0, P1, P2);
    P0 = P1;
    P1 = P2;
    rC = rN;
  }
  {
    const int z = d0 + DCHUNK - 1;
    Plane P2 = reduce_raw(rC);
    *(float4*)(ob + (size_t)z * HWn + r0 + w4) = mag4(P0, P1, P2);
  }
}

extern "C" void kernel_launch(void* const* d_in, const int* in_sizes, int n_in,
                              void* d_out, int out_size, void* d_ws, size_t ws_size,
                              hipStream_t stream) {
  const float* x = (const float*)d_in[0];
  float* out = (float*)d_out;

  dim3 block(BLOCK);
  dim3 grid(COLS / BLOCK, Dn / DCHUNK, BCn);  // (25, 40, 4) = 4000 blocks
  sobel3d_mag_kernel<<<grid, block, 0, stream>>>(x, out);
}

// Round 6
// 35.336 us; speedup vs baseline: 1.4355x; 1.4169x over previous
//
#include <hip/hip_runtime.h>
#include <math.h>

// Problem constants (from reference: x = (2,2,160,160,160) fp32)
#define BCn 4
#define Dn 160
#define Hn 160
#define Wn 160
#define HWn (Hn * Wn)
#define W4q (Wn / 4)        // 40 float4 groups per row
#define COLS (Hn * W4q)     // 6400 (h, q) columns per plane
#define DCHUNK 5
#define BLOCK 256

// Reduced per-plane state for 4 consecutive W outputs:
//   Rs = 3x3 window sums (feeds gd), Rd = row(h+1)-row(h-1) sums (feeds gh),
//   Cs = col(w+1)-col(w-1) sums (feeds gw).
struct Plane {
  float4 Rs, Rd, Cs;
};

// One z-plane: 3 coalesced float4 loads; the w-1 / w+4 halo comes from
// neighbor lanes' registers via shuffle (DS pipe) instead of 6 scalar
// global loads (which each cost ~16 L1 line-touches for 256 useful bytes —
// the R0-R5 bottleneck). Row-edge lanes (q==0 / q==W4q-1) are exactly the
// replicate-clamp cases -> select own .x/.w. Wave-edge lanes (lane 0/63
// mid-row) take a 1-lane predicated scalar load (~1 line each).
__device__ __forceinline__ Plane load_plane(const float* __restrict__ xb, int zz,
                                            int rm, int r0, int rp, int w4,
                                            bool ql, bool qr, bool fixL, bool fixR) {
  const int zc = zz < 0 ? 0 : (zz > Dn - 1 ? Dn - 1 : zz);
  const float* p = xb + (size_t)zc * HWn;

  const float4 vm = *(const float4*)(p + rm + w4);
  const float4 v0 = *(const float4*)(p + r0 + w4);
  const float4 vp = *(const float4*)(p + rp + w4);

  // Cross-lane halo (uniform control flow here: whole wave executes).
  float lA = __shfl_up(vm.w, 1);
  float lB = __shfl_up(v0.w, 1);
  float lC = __shfl_up(vp.w, 1);
  float rA = __shfl_down(vm.x, 1);
  float rB = __shfl_down(v0.x, 1);
  float rC = __shfl_down(vp.x, 1);

  // Wave-boundary fixups: single active lane -> ~1 line-touch each.
  if (fixL) {
    lA = p[rm + w4 - 1];
    lB = p[r0 + w4 - 1];
    lC = p[rp + w4 - 1];
  }
  if (fixR) {
    rA = p[rm + w4 + 4];
    rB = p[r0 + w4 + 4];
    rC = p[rp + w4 + 4];
  }

  // Replicate clamp at row edges.
  const float m0 = ql ? vm.x : lA;
  const float c0 = ql ? v0.x : lB;
  const float q0 = ql ? vp.x : lC;
  const float m5 = qr ? vm.w : rA;
  const float c5 = qr ? v0.w : rB;
  const float q5 = qr ? vp.w : rC;

  // Column sums over the 3 rows (6 columns: w-1 .. w+4)
  const float s0 = m0 + c0 + q0;
  const float s1 = vm.x + v0.x + vp.x;
  const float s2 = vm.y + v0.y + vp.y;
  const float s3 = vm.z + v0.z + vp.z;
  const float s4 = vm.w + v0.w + vp.w;
  const float s5 = m5 + c5 + q5;
  // Column diffs row(h+1) - row(h-1)
  const float d0 = q0 - m0;
  const float d1 = vp.x - vm.x;
  const float d2 = vp.y - vm.y;
  const float d3 = vp.z - vm.z;
  const float d4 = vp.w - vm.w;
  const float d5 = q5 - m5;

  Plane out;
  const float t12 = s1 + s2, t23 = s2 + s3, t34 = s3 + s4;
  out.Rs.x = s0 + t12;
  out.Rs.y = t12 + s3;
  out.Rs.z = t23 + s4;
  out.Rs.w = t34 + s5;
  out.Rd.x = d0 + d1 + d2;
  out.Rd.y = d1 + d2 + d3;
  out.Rd.z = d2 + d3 + d4;
  out.Rd.w = d3 + d4 + d5;
  out.Cs.x = s2 - s0;
  out.Cs.y = s3 - s1;
  out.Cs.z = s4 - s2;
  out.Cs.w = s5 - s3;
  return out;
}

__device__ __forceinline__ float4 mag4(const Plane& P0, const Plane& P1,
                                       const Plane& P2) {
  const float gdx = P2.Rs.x - P0.Rs.x;
  const float gdy = P2.Rs.y - P0.Rs.y;
  const float gdz = P2.Rs.z - P0.Rs.z;
  const float gdw = P2.Rs.w - P0.Rs.w;
  const float ghx = P0.Rd.x + P1.Rd.x + P2.Rd.x;
  const float ghy = P0.Rd.y + P1.Rd.y + P2.Rd.y;
  const float ghz = P0.Rd.z + P1.Rd.z + P2.Rd.z;
  const float ghw = P0.Rd.w + P1.Rd.w + P2.Rd.w;
  const float gwx = P0.Cs.x + P1.Cs.x + P2.Cs.x;
  const float gwy = P0.Cs.y + P1.Cs.y + P2.Cs.y;
  const float gwz = P0.Cs.z + P1.Cs.z + P2.Cs.z;
  const float gww = P0.Cs.w + P1.Cs.w + P2.Cs.w;
  float4 g;
  g.x = sqrtf(gdx * gdx + ghx * ghx + gwx * gwx);
  g.y = sqrtf(gdy * gdy + ghy * ghy + gwy * gwy);
  g.z = sqrtf(gdz * gdz + ghz * ghz + gwz * gwz);
  g.w = sqrtf(gdw * gdw + ghw * ghw + gww * gww);
  return g;
}

__global__ __launch_bounds__(BLOCK) void sobel3d_mag_kernel(
    const float* __restrict__ x, float* __restrict__ out) {
  const int col4 = blockIdx.x * BLOCK + threadIdx.x;  // (h, q), 0..6399
  const int h = col4 / W4q;
  const int q = col4 - h * W4q;
  const int w4 = q * 4;
  const int bc = blockIdx.z;
  const int d0 = blockIdx.y * DCHUNK;

  const float* xb = x + (size_t)bc * Dn * HWn;
  float* ob = out + (size_t)bc * Dn * HWn;

  const int hm = (h > 0) ? h - 1 : 0;
  const int hp = (h < Hn - 1) ? h + 1 : Hn - 1;
  const int rm = hm * Wn;
  const int r0 = h * Wn;
  const int rp = hp * Wn;

  const int lane = threadIdx.x & 63;
  const bool ql = (q == 0);
  const bool qr = (q == W4q - 1);
  const bool fixL = (lane == 0) && !ql;    // left halo not in this wave
  const bool fixR = (lane == 63) && !qr;   // right halo not in this wave

  Plane P0 = load_plane(xb, d0 - 1, rm, r0, rp, w4, ql, qr, fixL, fixR);
  Plane P1 = load_plane(xb, d0, rm, r0, rp, w4, ql, qr, fixL, fixR);

#pragma unroll
  for (int i = 0; i < DCHUNK; ++i) {
    const int z = d0 + i;
    Plane P2 = load_plane(xb, z + 1, rm, r0, rp, w4, ql, qr, fixL, fixR);
    *(float4*)(ob + (size_t)z * HWn + r0 + w4) = mag4(P0, P1, P2);
    P0 = P1;
    P1 = P2;
  }
}

extern "C" void kernel_launch(void* const* d_in, const int* in_sizes, int n_in,
                              void* d_out, int out_size, void* d_ws, size_t ws_size,
                              hipStream_t stream) {
  const float* x = (const float*)d_in[0];
  float* out = (float*)d_out;

  dim3 block(BLOCK);
  dim3 grid(COLS / BLOCK, Dn / DCHUNK, BCn);  // (25, 32, 4) = 3200 blocks
  sobel3d_mag_kernel<<<grid, block, 0, stream>>>(x, out);
}